// Round 7
// baseline (841.039 us; speedup 1.0000x reference)
//
#include <hip/hip_runtime.h>

// ---------------------------------------------------------------------------
// metaLinear: y[t,o] = sum_j x2[t,j] * ( x1[t,:]@W[j*64+o,:] + bvec[j*64+o] )
//   T=16384, IN1=256, IN2=64 (j), OUT=64 (o).
// Round 7: R6's 64x64-per-wave dataflow (A-reuse x2 from L1, B-reuse x2 from
// registers) with a register budget that actually fits:
//   - K split into 4 passes (4 ks each): bfrag = 8 frags (32 VGPR) per pass
//   - A (W frags) loaded once per j, 8 frags (32 VGPR), NO double buffer
//   - tile chains serialized in ot-pairs: only 2 w-partials (32) live
//   - yacc[4] (64) persistent; total ~190 < 256 -> 2 waves/SIMD, no spill
// Latency hiding via TLP only (2 waves/SIMD saturate the MFMA pipe even with
// a dumb load->wait->compute loop), not via SW pipelining the compiler must
// register-allocate. 512-thr WGs, in-WG j-split (8 j per wave), verified
// R6 epilogue: 4-phase LDS reduce -> bias MFMA -> store.
// ---------------------------------------------------------------------------

#define FRAG_SHORTS 512                  // 64 lanes * 8 bf16
#define JSTRIDE (2 * 16 * FRAG_SHORTS)   // 16384 shorts per j (2 ot, 16 ks)
#define SX_STRIDE 72                     // shorts per staged x1 row (144 B)
#define BV_OFF 16384                     // shorts; bvec bf16 region (8 KB)

typedef __bf16 bf16x8 __attribute__((ext_vector_type(8)));
typedef float  f32x16 __attribute__((ext_vector_type(16)));

static __device__ __forceinline__ unsigned short f2bf(float f) {
  union { float f; unsigned u; } v; v.f = f;
  unsigned r = v.u + 0x7FFFu + ((v.u >> 16) & 1u);   // RNE
  return (unsigned short)(r >> 16);
}

// Wf[((j*2+ot)*16 + ks)*512 + lane*8 + e] =
//     bf16( W[row = 64j+32ot+(lane&31)][col = 16ks + 8*(lane>>5) + e] )
__global__ void prep_w(const float* __restrict__ W, unsigned short* __restrict__ Wf) {
  int wv   = threadIdx.x >> 6;
  int lane = threadIdx.x & 63;
  int l31  = lane & 31;
  int lg   = lane >> 5;
  int task = blockIdx.x * 4 + wv;       // 0..2047
  int ks   = task & 15;
  int joh  = task >> 4;                 // j*2+ot
  int r    = 32 * joh + l31;
  int col  = ks * 16 + lg * 8;

  const float4* src = (const float4*)(W + (size_t)r * 256 + col);
  float4 a = src[0], b = src[1];
  ushort4 u0, u1;
  u0.x = f2bf(a.x); u0.y = f2bf(a.y); u0.z = f2bf(a.z); u0.w = f2bf(a.w);
  u1.x = f2bf(b.x); u1.y = f2bf(b.y); u1.z = f2bf(b.z); u1.w = f2bf(b.w);
  size_t fb = ((size_t)joh * 16 + ks) * FRAG_SHORTS;
  *(ushort4*)&Wf[fb + lane * 8 + 0] = u0;
  *(ushort4*)&Wf[fb + lane * 8 + 4] = u1;
}

// Grid: 256 WGs x 512 threads (8 waves). WG g owns tokens [g*64, +64) and all
// 64 outputs; wave wv handles j in [8wv, 8wv+8). Wave tile = 64 tok x 64 o:
// 4 sub-tiles (tt,ot), yacc[tt*2+ot]; owner wave of tile i is wave i (i<4).
__global__ __launch_bounds__(512, 2)
void meta_main(const float* __restrict__ x1, const float* __restrict__ x2,
               const float* __restrict__ bvec,
               const unsigned short* __restrict__ Wf, float* __restrict__ out) {
  // shorts [0,16384) = 32 KB: x1 staging (first 4608) / epilogue reduce region
  // shorts [16384,20480) = 8 KB: bvec bf16
  __shared__ unsigned short sX1[20480];

  const int tid  = threadIdx.x;
  const int lane = tid & 63;
  const int wv   = tid >> 6;            // 0..7
  const int l31  = lane & 31;
  const int lg   = lane >> 5;
  const long tok0 = (long)blockIdx.x * 64;

  // ---- once: bvec fp32 -> bf16 into its region ----
  {
    #pragma unroll
    for (int c = 0; c < 2; ++c) {
      int i = c * 512 + tid;            // 1024 float4
      float4 v = ((const float4*)bvec)[i];
      ushort4 u;
      u.x = f2bf(v.x); u.y = f2bf(v.y); u.z = f2bf(v.z); u.w = f2bf(v.w);
      *(ushort4*)&sX1[BV_OFF + i * 4] = u;
    }
  }

  // ---- once: x2 scalars for this wave's 8 j's, both token tiles ----
  float xa[8], xb[8];
  {
    const float* r0 = x2 + (tok0 + l31) * 64 + 8 * wv;
    const float* r1 = x2 + (tok0 + 32 + l31) * 64 + 8 * wv;
    float4 p0 = *(const float4*)r0, p1 = *(const float4*)(r0 + 4);
    float4 p2 = *(const float4*)r1, p3 = *(const float4*)(r1 + 4);
    xa[0] = p0.x; xa[1] = p0.y; xa[2] = p0.z; xa[3] = p0.w;
    xa[4] = p1.x; xa[5] = p1.y; xa[6] = p1.z; xa[7] = p1.w;
    xb[0] = p2.x; xb[1] = p2.y; xb[2] = p2.z; xb[3] = p2.w;
    xb[4] = p3.x; xb[5] = p3.y; xb[6] = p3.z; xb[7] = p3.w;
  }

  f32x16 yacc[4];
  #pragma unroll
  for (int t = 0; t < 4; ++t)
    #pragma unroll
    for (int r = 0; r < 16; ++r) yacc[t][r] = 0.0f;

  // ---- 4 K-passes: stage x1 cols [64kp,+64), then 8 j-steps of 16 MFMA ----
  for (int kp = 0; kp < 4; ++kp) {
    __syncthreads();                    // prior pass's bfrag reads done
    {
      const float4* src = (const float4*)(x1 + tok0 * 256 + kp * 64);
      #pragma unroll
      for (int it = 0; it < 2; ++it) {
        int fi4 = it * 512 + tid;       // 1024 float4 = 64 rows x 16
        int row = fi4 >> 4;
        int c4  = fi4 & 15;
        float4 v = src[(size_t)row * 64 + c4];
        ushort4 b;
        b.x = f2bf(v.x); b.y = f2bf(v.y); b.z = f2bf(v.z); b.w = f2bf(v.w);
        *(ushort4*)&sX1[row * SX_STRIDE + c4 * 4] = b;
      }
    }
    __syncthreads();

    bf16x8 bf0[4], bf1[4];
    #pragma unroll
    for (int q = 0; q < 4; ++q) {
      bf0[q] = *(const bf16x8*)&sX1[l31 * SX_STRIDE + q * 16 + lg * 8];
      bf1[q] = *(const bf16x8*)&sX1[(32 + l31) * SX_STRIDE + q * 16 + lg * 8];
    }

    const unsigned short* wpp =
        Wf + lane * 8 + (size_t)(4 * kp) * FRAG_SHORTS + (size_t)(8 * wv) * JSTRIDE;

    #pragma unroll
    for (int jj = 0; jj < 8; ++jj) {
      const unsigned short* pj = wpp + (size_t)jj * JSTRIDE;
      bf16x8 A0[4], A1[4];
      #pragma unroll
      for (int q = 0; q < 4; ++q) {
        A0[q] = *(const bf16x8*)(pj + q * FRAG_SHORTS);           // ot=0
        A1[q] = *(const bf16x8*)(pj + 8192 + q * FRAG_SHORTS);    // ot=1
      }
      // ot=0 pair: tiles (tt0,ot0)->yacc[0], (tt1,ot0)->yacc[2]
      {
        f32x16 w0, w1;
        #pragma unroll
        for (int r = 0; r < 16; ++r) { w0[r] = 0.0f; w1[r] = 0.0f; }
        #pragma unroll
        for (int q = 0; q < 4; ++q) {
          w0 = __builtin_amdgcn_mfma_f32_32x32x16_bf16(A0[q], bf0[q], w0, 0, 0, 0);
          w1 = __builtin_amdgcn_mfma_f32_32x32x16_bf16(A0[q], bf1[q], w1, 0, 0, 0);
        }
        #pragma unroll
        for (int r = 0; r < 16; ++r) {
          yacc[0][r] += xa[jj] * w0[r];
          yacc[2][r] += xb[jj] * w1[r];
        }
      }
      // ot=1 pair: tiles (tt0,ot1)->yacc[1], (tt1,ot1)->yacc[3]
      {
        f32x16 w0, w1;
        #pragma unroll
        for (int r = 0; r < 16; ++r) { w0[r] = 0.0f; w1[r] = 0.0f; }
        #pragma unroll
        for (int q = 0; q < 4; ++q) {
          w0 = __builtin_amdgcn_mfma_f32_32x32x16_bf16(A1[q], bf0[q], w0, 0, 0, 0);
          w1 = __builtin_amdgcn_mfma_f32_32x32x16_bf16(A1[q], bf1[q], w1, 0, 0, 0);
        }
        #pragma unroll
        for (int r = 0; r < 16; ++r) {
          yacc[1][r] += xa[jj] * w0[r];
          yacc[3][r] += xb[jj] * w1[r];
        }
      }
    }
  }

  // ---- epilogue: 4-phase LDS all-reduce (8 waves -> owner waves 0..3) ----
  float* R = (float*)sX1;               // 32 KB region (bvec region disjoint)
  #pragma unroll
  for (int t = 0; t < 4; ++t) {
    __syncthreads();                    // region free / prior phase done
    #pragma unroll
    for (int q4 = 0; q4 < 4; ++q4) {
      float4 v;
      v.x = yacc[t][4 * q4 + 0]; v.y = yacc[t][4 * q4 + 1];
      v.z = yacc[t][4 * q4 + 2]; v.w = yacc[t][4 * q4 + 3];
      *(float4*)&R[wv * 1024 + lane * 16 + q4 * 4] = v;
    }
    __syncthreads();
    if (wv == t) {
      #pragma unroll
      for (int s = 0; s < 8; ++s) {
        if (s == t) continue;
        #pragma unroll
        for (int q4 = 0; q4 < 4; ++q4) {
          float4 v = *(const float4*)&R[s * 1024 + lane * 16 + q4 * 4];
          yacc[t][4 * q4 + 0] += v.x; yacc[t][4 * q4 + 1] += v.y;
          yacc[t][4 * q4 + 2] += v.z; yacc[t][4 * q4 + 3] += v.w;
        }
      }
    }
  }

  // ---- owner waves: bias matmul (y += x2 @ Bmat) + store ----
  if (wv < 4) {
    const int tt = wv >> 1, ot = wv & 1;
    const __bf16* bb = (const __bf16*)(sX1 + BV_OFF);
    f32x16 acc = yacc[wv];
    #pragma unroll
    for (int k = 0; k < 4; ++k) {
      bf16x8 Af, Bf;
      #pragma unroll
      for (int e = 0; e < 8; ++e)       // A[m=o][k'=j'] = bvec[j'*64+o]
        Af[e] = bb[(16 * k + 8 * lg + e) * 64 + 32 * ot + l31];
      const float* xr = x2 + (tok0 + tt * 32 + l31) * 64 + 16 * k + 8 * lg;
      float4 p0 = *(const float4*)xr;
      float4 p1 = *(const float4*)(xr + 4);
      Bf[0] = (__bf16)p0.x; Bf[1] = (__bf16)p0.y; Bf[2] = (__bf16)p0.z; Bf[3] = (__bf16)p0.w;
      Bf[4] = (__bf16)p1.x; Bf[5] = (__bf16)p1.y; Bf[6] = (__bf16)p1.z; Bf[7] = (__bf16)p1.w;
      acc = __builtin_amdgcn_mfma_f32_32x32x16_bf16(Af, Bf, acc, 0, 0, 0);
    }
    // D row o_local = (r&3)+8*(r>>2)+4*lg, col = token = l31
    float* yout = out + (tok0 + tt * 32 + l31) * 64 + ot * 32;
    #pragma unroll
    for (int q4 = 0; q4 < 4; ++q4) {
      float4 v;
      v.x = acc[4 * q4 + 0]; v.y = acc[4 * q4 + 1];
      v.z = acc[4 * q4 + 2]; v.w = acc[4 * q4 + 3];
      *(float4*)&yout[q4 * 8 + 4 * lg] = v;
    }
  }
}

extern "C" void kernel_launch(void* const* d_in, const int* in_sizes, int n_in,
                              void* d_out, int out_size, void* d_ws, size_t ws_size,
                              hipStream_t stream) {
  const float* x1 = (const float*)d_in[0];   // (4,4096,256) f32
  const float* x2 = (const float*)d_in[1];   // (4,4096,64)  f32
  const float* W  = (const float*)d_in[2];   // (4096,256)   f32
  const float* bv = (const float*)d_in[3];   // (4096,)      f32
  float* y = (float*)d_out;                  // (4,4096,64)  f32
  unsigned short* Wf = (unsigned short*)d_ws;  // 64*16384*2 = 2,097,152 B

  prep_w<<<512, 256, 0, stream>>>(W, Wf);
  meta_main<<<256, 512, 0, stream>>>(x1, x2, bv, Wf, y);
}